// Round 1
// baseline (426.852 us; speedup 1.0000x reference)
//
#include <hip/hip_runtime.h>

#define TDIM 256
#define THEADS 8
#define TB 32
#define TN 8192
#define NPAIR (TN/2)               // 4096
#define BLK_PER_B 16
#define WAVES_PB 4
#define GW_PER_B (BLK_PER_B*WAVES_PB)   // 64 waves per batch
#define ITERS (NPAIR/GW_PER_B)          // 64 pairs per wave
#define ACC_PER_B 2312                  // Y 8*256 + E 8 + S 256

__device__ __forceinline__ float xr(float v, int m) { return v + __shfl_xor(v, m, 64); }

__global__ void tmca_zero(float* __restrict__ acc, int n) {
  int i = blockIdx.x * 256 + threadIdx.x;
  if (i < n) acc[i] = 0.0f;
}

// q[b,t] = class_token[b]·W_q[:,t] + b_q[t]
__global__ void tmca_qproj(const float* __restrict__ ct, const float* __restrict__ Wq,
                           const float* __restrict__ bq, float* __restrict__ q) {
  int b = blockIdx.x, t = threadIdx.x;
  __shared__ float s[TDIM];
  s[t] = ct[b * TDIM + t];
  __syncthreads();
  float a = bq[t];
  for (int c = 0; c < TDIM; ++c) a = fmaf(s[c], Wq[c * TDIM + t], a);
  q[b * TDIM + t] = a;
}

// w1[b,g,c] = (1/sqrt(32)) * sum_h W_t1[h,g] * sum_d W_kv[c, 32h+d] * q[b,32h+d]
__global__ void tmca_w1(const float* __restrict__ q, const float* __restrict__ Wkv,
                        const float* __restrict__ Wt1, float* __restrict__ w1) {
  int b = blockIdx.x, c = threadIdx.x;
  __shared__ float sq[TDIM];
  __shared__ float st1[THEADS * THEADS];
  sq[c] = q[b * TDIM + c];
  if (c < THEADS * THEADS) st1[c] = Wt1[c];
  __syncthreads();
  float ph[THEADS];
  #pragma unroll
  for (int h = 0; h < THEADS; ++h) {
    float a = 0.0f;
    #pragma unroll 8
    for (int d = 0; d < 32; ++d) a = fmaf(Wkv[c * 512 + h * 32 + d], sq[h * 32 + d], a);
    ph[h] = a;
  }
  const float inv = 0.17677669529663687f;  // 1/sqrt(32)
  #pragma unroll
  for (int g = 0; g < THEADS; ++g) {
    float a = 0.0f;
    #pragma unroll
    for (int h = 0; h < THEADS; ++h) a = fmaf(ph[h], st1[h * THEADS + g], a);
    w1[(b * THEADS + g) * TDIM + c] = a * inv;
  }
}

// Streaming pass: per (b,g) accumulate E = sum_n mask*exp(s2), Y[c] = sum_n mask*exp(s2)*X[n,c],
// and S[c] = sum_n X[n,c].  Wave handles 2 tokens (half-wave each), lane owns 8 channels.
__global__ __launch_bounds__(256, 2) void tmca_main(
    const float* __restrict__ X, const int* __restrict__ mask,
    const float* __restrict__ w1, float* __restrict__ acc) {
  const int b = blockIdx.y;
  const int bk = blockIdx.x;
  const int tid = threadIdx.x;
  const int wv = tid >> 6;
  const int lane = tid & 63;
  const int half = lane >> 5;
  const int j = lane & 31;
  const int gw = bk * WAVES_PB + wv;

  const float4* w1b = (const float4*)(w1 + (size_t)b * THEADS * TDIM);
  float4 wg0[8], wg1[8];
  #pragma unroll
  for (int g = 0; g < 8; ++g) {
    wg0[g] = w1b[g * 64 + j];
    wg1[g] = w1b[g * 64 + 32 + j];
  }

  float4 Y0[8], Y1[8];
  float E[8];
  float4 S0 = make_float4(0, 0, 0, 0), S1 = make_float4(0, 0, 0, 0);
  #pragma unroll
  for (int g = 0; g < 8; ++g) {
    Y0[g] = make_float4(0, 0, 0, 0);
    Y1[g] = make_float4(0, 0, 0, 0);
    E[g] = 0.0f;
  }

  const float4* Xb = (const float4*)(X + (size_t)b * TN * TDIM);
  const int* mb = mask + b * TN;

  int p = gw;
  int n0 = 2 * p + half;
  float4 a0 = Xb[(size_t)n0 * 64 + j];
  float4 a1 = Xb[(size_t)n0 * 64 + 32 + j];
  int mk = mb[n0];

  for (int it = 0; it < ITERS; ++it) {
    float4 x0 = a0, x1 = a1;
    float fm = (float)mk;
    if (it + 1 < ITERS) {  // uniform branch: prefetch next pair
      int n2 = 2 * (p + GW_PER_B) + half;
      a0 = Xb[(size_t)n2 * 64 + j];
      a1 = Xb[(size_t)n2 * 64 + 32 + j];
      mk = mb[n2];
    }
    p += GW_PER_B;

    float pg[8];
    #pragma unroll
    for (int g = 0; g < 8; ++g) {
      pg[g] = x0.x * wg0[g].x + x0.y * wg0[g].y + x0.z * wg0[g].z + x0.w * wg0[g].w
            + x1.x * wg1[g].x + x1.y * wg1[g].y + x1.z * wg1[g].z + x1.w * wg1[g].w;
    }
    #pragma unroll
    for (int st = 1; st <= 16; st <<= 1) {
      #pragma unroll
      for (int g = 0; g < 8; ++g) pg[g] += __shfl_xor(pg[g], st, 64);
    }
    #pragma unroll
    for (int g = 0; g < 8; ++g) {
      float e = __expf(pg[g]) * fm;
      E[g] += e;
      Y0[g].x = fmaf(e, x0.x, Y0[g].x);
      Y0[g].y = fmaf(e, x0.y, Y0[g].y);
      Y0[g].z = fmaf(e, x0.z, Y0[g].z);
      Y0[g].w = fmaf(e, x0.w, Y0[g].w);
      Y1[g].x = fmaf(e, x1.x, Y1[g].x);
      Y1[g].y = fmaf(e, x1.y, Y1[g].y);
      Y1[g].z = fmaf(e, x1.z, Y1[g].z);
      Y1[g].w = fmaf(e, x1.w, Y1[g].w);
    }
    S0.x += x0.x; S0.y += x0.y; S0.z += x0.z; S0.w += x0.w;
    S1.x += x1.x; S1.y += x1.y; S1.z += x1.z; S1.w += x1.w;
  }

  // combine the two token-halves of the wave
  #pragma unroll
  for (int g = 0; g < 8; ++g) {
    Y0[g].x = xr(Y0[g].x, 32); Y0[g].y = xr(Y0[g].y, 32);
    Y0[g].z = xr(Y0[g].z, 32); Y0[g].w = xr(Y0[g].w, 32);
    Y1[g].x = xr(Y1[g].x, 32); Y1[g].y = xr(Y1[g].y, 32);
    Y1[g].z = xr(Y1[g].z, 32); Y1[g].w = xr(Y1[g].w, 32);
    E[g] = xr(E[g], 32);
  }
  S0.x = xr(S0.x, 32); S0.y = xr(S0.y, 32); S0.z = xr(S0.z, 32); S0.w = xr(S0.w, 32);
  S1.x = xr(S1.x, 32); S1.y = xr(S1.y, 32); S1.z = xr(S1.z, 32); S1.w = xr(S1.w, 32);

  // block reduction in LDS, then one atomicAdd set per block
  __shared__ float red[WAVES_PB][ACC_PER_B];
  float* sl = red[wv];
  if (lane < 32) {
    #pragma unroll
    for (int g = 0; g < 8; ++g) {
      ((float4*)(sl + g * TDIM))[j] = Y0[g];
      ((float4*)(sl + g * TDIM + 128))[j] = Y1[g];
    }
    ((float4*)(sl + 2056))[j] = S0;
    ((float4*)(sl + 2056 + 128))[j] = S1;
    if (lane == 0) {
      #pragma unroll
      for (int g = 0; g < 8; ++g) sl[2048 + g] = E[g];
    }
  }
  __syncthreads();
  float* gb = acc + b * ACC_PER_B;
  for (int idx = tid; idx < ACC_PER_B; idx += 256) {
    float v = red[0][idx] + red[1][idx] + red[2][idx] + red[3][idx];
    atomicAdd(gb + idx, v);
  }
}

// z[g2,c] = sum_g Wt2[g,g2]*Y[g,c]/E[g] + bt2[g2]*S[c]
// out_pre[32g2+d] = z[g2]·Wkv[:,256+32g2+d] + T[g2]*bkv[256+32g2+d],  T = colsum(Wt2) + N*bt2
// out = out_pre @ Wout + bout
__global__ void tmca_fin(const float* __restrict__ acc, const float* __restrict__ Wkv,
                         const float* __restrict__ bkv, const float* __restrict__ Wt2,
                         const float* __restrict__ bt2, const float* __restrict__ Wout,
                         const float* __restrict__ bout, float* __restrict__ out) {
  int b = blockIdx.x, t = threadIdx.x;
  __shared__ float z[THEADS][TDIM];
  __shared__ float opre[TDIM];
  __shared__ float sWt2[THEADS * THEADS];
  __shared__ float sE[THEADS];
  __shared__ float sbt2[THEADS];
  const float* ab = acc + b * ACC_PER_B;
  if (t < THEADS * THEADS) sWt2[t] = Wt2[t];
  if (t < THEADS) { sE[t] = ab[2048 + t]; sbt2[t] = bt2[t]; }
  __syncthreads();
  float Yc[THEADS];
  #pragma unroll
  for (int g = 0; g < THEADS; ++g) Yc[g] = ab[g * TDIM + t] / sE[g];
  float Sc = ab[2056 + t];
  #pragma unroll
  for (int g2 = 0; g2 < THEADS; ++g2) {
    float a = 0.0f;
    #pragma unroll
    for (int g = 0; g < THEADS; ++g) a = fmaf(sWt2[g * THEADS + g2], Yc[g], a);
    z[g2][t] = a + sbt2[g2] * Sc;
  }
  __syncthreads();
  {
    int g2 = t >> 5;
    float T = 0.0f;
    #pragma unroll
    for (int g = 0; g < THEADS; ++g) T += sWt2[g * THEADS + g2];
    T += (float)TN * sbt2[g2];
    float a = 0.0f;
    for (int c = 0; c < TDIM; ++c) a = fmaf(z[g2][c], Wkv[c * 512 + 256 + t], a);
    opre[t] = a + T * bkv[256 + t];
  }
  __syncthreads();
  float a = bout[t];
  for (int c = 0; c < TDIM; ++c) a = fmaf(opre[c], Wout[c * TDIM + t], a);
  out[b * TDIM + t] = a;
}

extern "C" void kernel_launch(void* const* d_in, const int* in_sizes, int n_in,
                              void* d_out, int out_size, void* d_ws, size_t ws_size,
                              hipStream_t stream) {
  const float* X    = (const float*)d_in[0];
  const float* ct   = (const float*)d_in[1];
  const int*   msk  = (const int*)d_in[2];
  const float* Wkv  = (const float*)d_in[3];
  const float* bkv  = (const float*)d_in[4];
  const float* Wq   = (const float*)d_in[5];
  const float* bq   = (const float*)d_in[6];
  const float* Wt1  = (const float*)d_in[7];
  // d_in[8] = b_t1: constant shift per (b,g) -> softmax-invariant, unused
  const float* Wt2  = (const float*)d_in[9];
  const float* bt2  = (const float*)d_in[10];
  const float* Wout = (const float*)d_in[11];
  const float* bout = (const float*)d_in[12];
  float* out = (float*)d_out;

  float* ws  = (float*)d_ws;          // ws usage: 8192 + 65536 + 32*2312 floats (~590 KB)
  float* q   = ws;
  float* w1  = ws + 8192;
  float* acc = ws + 8192 + 65536;
  const int accN = TB * ACC_PER_B;

  hipLaunchKernelGGL(tmca_zero, dim3((accN + 255) / 256), dim3(256), 0, stream, acc, accN);
  hipLaunchKernelGGL(tmca_qproj, dim3(TB), dim3(256), 0, stream, ct, Wq, bq, q);
  hipLaunchKernelGGL(tmca_w1, dim3(TB), dim3(256), 0, stream, q, Wkv, Wt1, w1);
  hipLaunchKernelGGL(tmca_main, dim3(BLK_PER_B, TB), dim3(256), 0, stream, X, msk, w1, acc);
  hipLaunchKernelGGL(tmca_fin, dim3(TB), dim3(256), 0, stream, acc, Wkv, bkv, Wt2, bt2,
                     Wout, bout, out);
}